// Round 1
// 1103.620 us; speedup vs baseline: 1.0843x; 1.0843x over previous
//
#include <hip/hip_runtime.h>
#include <math.h>

#define NB   256
#define NPG  2048
#define DD   128
#define DEGC 16
#define NTOT (NB * NPG)      // 524288 nodes
#define ETOT (NTOT * DEGC)   // 8388608 edges
#define KK   (NPG / 2)       // 1024 kept per graph
#define EPG  (NPG * DEGC)    // 32768 edges per graph
#define MAXK 48              // per-node in-degree cap for LDS path (P(exceed) ~ 1e-9/node)
#define ROWW 49              // 49 coprime with 32 banks -> conflict-free row bases

// ---------------- K1: h = x @ W  (half-wave per node, float4) ----------------
__global__ __launch_bounds__(256) void k_h(const float* __restrict__ x,
                                           const float* __restrict__ W,
                                           float* __restrict__ h) {
    int lane = threadIdx.x & 63;
    int wv   = threadIdx.x >> 6;
    int half = lane >> 5;
    int sub  = lane & 31;
    int node = blockIdx.x * 8 + wv * 2 + half;
    const float4* x4 = (const float4*)x;
    const float4* W4 = (const float4*)W;
    float4 xv = x4[(size_t)node * 32 + sub];
    float4 wv4 = W4[sub];
    float p = xv.x * wv4.x + xv.y * wv4.y + xv.z * wv4.z + xv.w * wv4.w;
    #pragma unroll
    for (int off = 16; off >= 1; off >>= 1) p += __shfl_xor(p, off, 64);
    if (sub == 0) h[node] = p;
}

// ---- K2: per-graph count + scan + scatter, one block per graph, LDS ----
// Scatters, in coalesced-read order:
//   epack[pos]  = (e_local << 8) | rank_in_bucket   (rank = arrival order)
//   pwsrc[pos]  = { w[e], __int_as_float(src_local) }
// Random 4B/8B writes are confined to this graph's L2-resident slabs.
__global__ __launch_bounds__(1024) void k_build(const int* __restrict__ src,
                                                const int* __restrict__ dst,
                                                const float* __restrict__ w,
                                                int* __restrict__ ptr_g,
                                                int* __restrict__ cnt_g,
                                                int* __restrict__ epack,
                                                float2* __restrict__ pwsrc) {
    int b = blockIdx.x, t = threadIdx.x;
    __shared__ int cnt[NPG];    // 8 KB
    __shared__ int cur[NPG];    // 8 KB
    __shared__ int start[NPG];  // 8 KB
    __shared__ int sums[1024];  // 4 KB
    const int*   dslab = dst + (size_t)b * EPG;
    const int*   sslab = src + (size_t)b * EPG;
    const float* wslab = w   + (size_t)b * EPG;
    // phase 1: zero + count
    cnt[t] = 0; cnt[t + 1024] = 0;
    __syncthreads();
    #pragma unroll
    for (int i = 0; i < EPG / 1024; i++) {
        int d = dslab[i * 1024 + t] - b * NPG;
        atomicAdd(&cnt[d], 1);
    }
    __syncthreads();
    // phase 2: exclusive scan over 2048 counters (2 per thread)
    int c0 = cnt[2 * t], c1 = cnt[2 * t + 1];
    sums[t] = c0 + c1;
    __syncthreads();
    for (int off = 1; off < 1024; off <<= 1) {
        int v = (t >= off) ? sums[t - off] : 0;
        __syncthreads();
        sums[t] += v;
        __syncthreads();
    }
    int excl = (t > 0) ? sums[t - 1] : 0;
    int p0 = excl;          // local offsets within graph slab
    int p1 = p0 + c0;
    cur[2 * t] = p0;   cur[2 * t + 1] = p1;
    start[2 * t] = p0; start[2 * t + 1] = p1;
    int base = b * EPG;
    ptr_g[b * NPG + 2 * t]     = base + p0;
    ptr_g[b * NPG + 2 * t + 1] = base + p1;
    cnt_g[b * NPG + 2 * t]     = c0;
    cnt_g[b * NPG + 2 * t + 1] = c1;
    __syncthreads();
    // phase 3: scatter packed edge key + payload (order arbitrary; k_deg sorts)
    #pragma unroll
    for (int i = 0; i < EPG / 1024; i++) {
        int e = i * 1024 + t;
        int d = dslab[e] - b * NPG;
        int pos = atomicAdd(&cur[d], 1);
        int rank = pos - start[d];            // < 256 (in-degree is ~Binom(32768,1/2048))
        epack[base + pos] = (e << 8) | rank;
        float2 r;
        r.x = wslab[e];
        r.y = __int_as_float(sslab[e] - b * NPG);
        pwsrc[base + pos] = r;
    }
}

// ---- K3: sort each node's bucket asc by edge id (np.add.at order) via packed
//      keys in LDS, permute the float2 payload in place using rank bits, and
//      compute deg = sum of sorted w + 1.  All global traffic sequential. ----
__global__ __launch_bounds__(128) void k_deg(const int* __restrict__ ptr,
                                             const int* __restrict__ cnt,
                                             int* __restrict__ epack,
                                             float* __restrict__ pw,   // (float*)pwsrc
                                             const float* __restrict__ w,
                                             const int* __restrict__ src,
                                             float* __restrict__ is_arr) {
    __shared__ int   ibuf[128 * ROWW];   // ~25 KB
    __shared__ float fbuf[128 * ROWW];   // ~25 KB
    int n = blockIdx.x * 128 + threadIdx.x;
    int*   row  = &ibuf[threadIdx.x * ROWW];
    float* rowf = &fbuf[threadIdx.x * ROWW];
    int beg = ptr[n], k = cnt[n];
    float s = 0.0f;
    if (k <= MAXK) {
        for (int i = 0; i < k; i++) row[i] = epack[beg + i];
        // insertion sort on packed key == sort ascending by edge id
        for (int i = 1; i < k; i++) {
            int v = row[i];
            int j = i - 1;
            while (j >= 0) {
                int u = row[j];
                if (u > v) { row[j + 1] = u; j--; } else break;
            }
            row[j + 1] = v;
        }
        // permute w field (.x) in place; accumulate deg in sorted order
        for (int i = 0; i < k; i++) rowf[i] = pw[2 * (beg + (row[i] & 255))];
        for (int i = 0; i < k; i++) { pw[2 * (beg + i)] = rowf[i]; s += rowf[i]; }
        // permute src field (.y) in place
        for (int i = 0; i < k; i++) rowf[i] = pw[2 * (beg + (row[i] & 255)) + 1];
        for (int i = 0; i < k; i++) pw[2 * (beg + i) + 1] = rowf[i];
    } else {
        // rare fallback: sort keys in global, regather payload from originals
        int b = n >> 11;              // n / NPG
        int ebase = b * EPG;
        for (int i = 1; i < k; i++) {
            int v = epack[beg + i];
            int j = i - 1;
            while (j >= 0) {
                int u = epack[beg + j];
                if (u > v) { epack[beg + j + 1] = u; j--; } else break;
            }
            epack[beg + j + 1] = v;
        }
        for (int i = 0; i < k; i++) {
            int eg = ebase + (epack[beg + i] >> 8);
            float wv = w[eg];
            pw[2 * (beg + i)]     = wv;
            pw[2 * (beg + i) + 1] = __int_as_float(src[eg] - b * NPG);
            s += wv;
        }
    }
    float deg = s + 1.0f;                 // matches ref: segment_sum(...) + 1.0
    is_arr[n] = 1.0f / sqrtf(deg);
}

// ---------------- K4: score — fully streaming edge payload, LDS h/is --------
__global__ __launch_bounds__(256) void k_score(const int* __restrict__ ptr,
                                               const int* __restrict__ cnt,
                                               const float2* __restrict__ pwsrc,
                                               const float* __restrict__ h,
                                               const float* __restrict__ is_arr,
                                               float* __restrict__ score) {
    __shared__ float sh_h[NPG];    // 8 KB
    __shared__ float sh_is[NPG];   // 8 KB
    int b = blockIdx.x >> 3;       // 8 blocks per graph (2048/256)
    for (int i = threadIdx.x; i < NPG; i += 256) {
        sh_h[i]  = h[(size_t)b * NPG + i];
        sh_is[i] = is_arr[(size_t)b * NPG + i];
    }
    __syncthreads();
    int n = blockIdx.x * 256 + threadIdx.x;
    int nl = n & (NPG - 1);
    int beg = ptr[n], k = cnt[n];
    float isd = sh_is[nl];
    float s = 0.0f;
    for (int i = 0; i < k; i++) {
        float2 r = pwsrc[beg + i];
        int sl = __float_as_int(r.y);
        float v = ((r.x * sh_is[sl]) * isd) * sh_h[sl];  // ref rounding order
        s += v;
    }
    s = s + sh_h[nl] * (isd * isd);       // self-loop term, ref rounding order
    score[n] = s;
}

// ------- K5: per-graph bitonic top-k (desc score, asc index ties) -----------
__global__ __launch_bounds__(1024) void k_topk(const float* __restrict__ score,
                                               int* __restrict__ topk,
                                               int* __restrict__ new_id,
                                               float* __restrict__ pngi) {
    int b = blockIdx.x, t = threadIdx.x;
    __shared__ unsigned long long key[NPG];
    for (int i = t; i < NPG; i += 1024) {
        float s = score[b * NPG + i];
        unsigned int u = __float_as_uint(s);
        u = (u & 0x80000000u) ? ~u : (u | 0x80000000u);  // ascending-order map
        unsigned int ks = ~u;                            // descending primary
        key[i] = ((unsigned long long)ks << 32) | (unsigned int)i;
    }
    __syncthreads();
    for (int k = 2; k <= NPG; k <<= 1) {
        for (int j = k >> 1; j > 0; j >>= 1) {
            int i = ((t & ~(j - 1)) << 1) | (t & (j - 1));
            int p = i | j;
            bool up = ((i & k) == 0);
            unsigned long long a = key[i], c = key[p];
            if ((a > c) == up) { key[i] = c; key[p] = a; }
            __syncthreads();
        }
    }
    int local = (int)(key[t] & 0xFFFFFFFFu);
    int node = b * NPG + local;
    int j = b * KK + t;
    topk[j] = node;
    new_id[node] = j;
    pngi[j] = (float)b;
}

// ---------------- K6: pooled_x = x[node] * tanh(score[node]) ----------------
__global__ __launch_bounds__(256) void k_gather(const float* __restrict__ x,
                                                const float* __restrict__ score,
                                                const int* __restrict__ topk,
                                                float* __restrict__ out) {
    int q = blockIdx.x * 256 + threadIdx.x;   // float4 index
    int row = q >> 5, c = q & 31;
    int node = topk[row];
    float g = tanhf(score[node]);
    const float4* x4 = (const float4*)x;
    float4 v = x4[(size_t)node * 32 + c];
    float4 o;
    o.x = v.x * g; o.y = v.y * g; o.z = v.z * g; o.w = v.w * g;
    ((float4*)out)[q] = o;
}

// ---------------- K7: edge remap + weight mask ----------------
__global__ __launch_bounds__(256) void k_edges(const int* __restrict__ src,
                                               const int* __restrict__ dst,
                                               const float* __restrict__ w,
                                               const int* __restrict__ new_id,
                                               float* __restrict__ pei0,
                                               float* __restrict__ pei1,
                                               float* __restrict__ pew) {
    int e = blockIdx.x * 256 + threadIdx.x;
    int s = src[e], d = dst[e];
    int ns = new_id[s], nd = new_id[d];
    bool m = (ns >= 0) && (nd >= 0);
    pei0[e] = m ? (float)ns : -1.0f;
    pei1[e] = m ? (float)nd : -1.0f;
    pew[e]  = m ? w[e] : 0.0f;
}

extern "C" void kernel_launch(void* const* d_in, const int* in_sizes, int n_in,
                              void* d_out, int out_size, void* d_ws, size_t ws_size,
                              hipStream_t stream) {
    const float* x   = (const float*)d_in[0];
    const int*   ei  = (const int*)d_in[1];
    const float* w   = (const float*)d_in[2];
    // d_in[3] = node_graph_index (unused: graphs are uniform)
    const float* W   = (const float*)d_in[4];
    const int* src = ei;
    const int* dst = ei + ETOT;

    // workspace layout
    char* ws = (char*)d_ws;
    float*  h      = (float*)(ws);                 // N floats
    float*  is_arr = h + NTOT;                     // N floats
    float*  score  = is_arr + NTOT;                // N floats
    int*    cnt    = (int*)(score + NTOT);         // N ints
    int*    ptr    = cnt + NTOT;                   // N ints
    int*    new_id = ptr + NTOT;                   // N ints
    int*    topk   = new_id + NTOT;                // B*K ints
    int*    epack  = topk + (size_t)NB * KK;       // E ints (packed keys)
    float2* pwsrc  = (float2*)(epack + (size_t)ETOT); // E float2 (w, src_local)

    // output layout (all float32)
    float* out_px   = (float*)d_out;                       // [B*K, D]
    float* out_pei0 = out_px + (size_t)NB * KK * DD;       // [E]
    float* out_pei1 = out_pei0 + ETOT;                     // [E]
    float* out_pew  = out_pei1 + ETOT;                     // [E]
    float* out_pngi = out_pew + ETOT;                      // [B*K]

    hipMemsetAsync(new_id, 0xFF, (size_t)NTOT * 4, stream);  // -1

    k_h<<<NTOT / 8, 256, 0, stream>>>(x, W, h);
    k_build<<<NB, 1024, 0, stream>>>(src, dst, w, ptr, cnt, epack, pwsrc);
    k_deg<<<NTOT / 128, 128, 0, stream>>>(ptr, cnt, epack, (float*)pwsrc, w, src, is_arr);
    k_score<<<NTOT / 256, 256, 0, stream>>>(ptr, cnt, pwsrc, h, is_arr, score);
    k_topk<<<NB, 1024, 0, stream>>>(score, topk, new_id, out_pngi);
    k_gather<<<(NB * KK * DD / 4) / 256, 256, 0, stream>>>(x, score, topk, out_px);
    k_edges<<<ETOT / 256, 256, 0, stream>>>(src, dst, w, new_id, out_pei0, out_pei1, out_pew);
}

// Round 4
// 793.411 us; speedup vs baseline: 1.5082x; 1.3910x over previous
//
#include <hip/hip_runtime.h>
#include <math.h>

#define NB   256
#define NPG  2048
#define DD   128
#define DEGC 16
#define NTOT (NB * NPG)      // 524288 nodes
#define ETOT (NTOT * DEGC)   // 8388608 edges
#define KK   (NPG / 2)       // 1024 kept per graph
#define EPG  (NPG * DEGC)    // 32768 edges per graph
#define NCB  16              // coarse buckets per graph (128 nodes each)
#define CBN  128             // nodes per coarse bucket
#define CAP  2560            // chunk capacity: mean 2048, sd 44 -> mean+11.6sd

// ---------------- K1: h = x @ W  (half-wave per node, float4) ----------------
__global__ __launch_bounds__(256) void k_h(const float* __restrict__ x,
                                           const float* __restrict__ W,
                                           float* __restrict__ h) {
    int lane = threadIdx.x & 63;
    int wv   = threadIdx.x >> 6;
    int half = lane >> 5;
    int sub  = lane & 31;
    int node = blockIdx.x * 8 + wv * 2 + half;
    const float4* x4 = (const float4*)x;
    const float4* W4 = (const float4*)W;
    float4 xv = x4[(size_t)node * 32 + sub];
    float4 wv4 = W4[sub];
    float p = xv.x * wv4.x + xv.y * wv4.y + xv.z * wv4.z + xv.w * wv4.w;
    #pragma unroll
    for (int off = 16; off >= 1; off >>= 1) p += __shfl_xor(p, off, 64);
    if (sub == 0) h[node] = p;
}

// ---- K2a: coarse partition, one block per graph. Edges scattered to 16
//      append-frontiers (dense lines -> no write amplification). Record:
//      ebws = {w, src_local as float bits}, ebe = (e_local<<7)|dst_low7. ----
__global__ __launch_bounds__(1024) void k_part(const int* __restrict__ src,
                                               const int* __restrict__ dst,
                                               const float* __restrict__ w,
                                               int* __restrict__ cptr_g,
                                               int* __restrict__ ccnt_g,
                                               float2* __restrict__ ebws,
                                               int* __restrict__ ebe) {
    int g = blockIdx.x, t = threadIdx.x;
    __shared__ int ccnt[NCB];
    __shared__ int ccur[NCB];
    const int*   dslab = dst + (size_t)g * EPG;
    const int*   sslab = src + (size_t)g * EPG;
    const float* wslab = w   + (size_t)g * EPG;
    if (t < NCB) ccnt[t] = 0;
    __syncthreads();
    // phase 1: count coarse buckets; keep local dst in registers (full unroll)
    int dloc[EPG / 1024];
    #pragma unroll
    for (int i = 0; i < EPG / 1024; i++) {
        dloc[i] = dslab[i * 1024 + t] - g * NPG;
        atomicAdd(&ccnt[dloc[i] >> 7], 1);
    }
    __syncthreads();
    // phase 2: tiny serial scan of 16
    if (t == 0) {
        int acc = 0;
        for (int b = 0; b < NCB; b++) {
            int c = ccnt[b];
            cptr_g[g * NCB + b] = acc;
            ccnt_g[g * NCB + b] = c;
            ccur[b] = acc;
            acc += c;
        }
    }
    __syncthreads();
    // phase 3: scatter to coarse frontiers
    size_t gb = (size_t)g * EPG;
    #pragma unroll
    for (int i = 0; i < EPG / 1024; i++) {
        int e = i * 1024 + t;
        int d = dloc[i];
        int pos = atomicAdd(&ccur[d >> 7], 1);
        ebe[gb + pos] = (e << 7) | (d & 127);
        float2 r;
        r.x = wslab[e];
        r.y = __int_as_float(sslab[e] - g * NPG);
        ebws[gb + pos] = r;
    }
}

// ---- K2b: fine scatter + per-node sort + deg, one block per (graph, coarse
//      bucket). Stages the ~16 KB chunk in LDS, sorts each node's edges asc by
//      edge id (np.add.at order), computes deg in sorted order, writes the
//      sorted payload back IN PLACE (coalesced) -> ebws becomes pwsrc. ----
__global__ __launch_bounds__(256) void k_fine(const int* __restrict__ cptr_g,
                                              const int* __restrict__ ccnt_g,
                                              float2* ebws,            // read+write (in place)
                                              const int* __restrict__ ebe,
                                              int* __restrict__ ptr,
                                              int* __restrict__ cnt,
                                              float* __restrict__ is_arr) {
    __shared__ int   skey[CAP];
    __shared__ float sw[CAP];
    __shared__ float sy[CAP];
    __shared__ int cnt_f[CBN];
    __shared__ int cur_f[CBN];
    __shared__ int base_f[CBN];
    __shared__ int tmp[CBN];
    int g = blockIdx.x >> 4, cb = blockIdx.x & 15, t = threadIdx.x;
    int cb_base = cptr_g[g * NCB + cb];
    int ncb     = ccnt_g[g * NCB + cb];
    size_t gb = (size_t)g * EPG + cb_base;
    if (t < CBN) cnt_f[t] = 0;
    __syncthreads();
    // pass A: fine counts
    for (int i = t; i < ncb; i += 256) atomicAdd(&cnt_f[ebe[gb + i] & 127], 1);
    __syncthreads();
    // scan 128 (Hillis-Steele)
    if (t < CBN) tmp[t] = cnt_f[t];
    __syncthreads();
    for (int off = 1; off < CBN; off <<= 1) {
        int v = 0;
        if (t < CBN && t >= off) v = tmp[t - off];
        __syncthreads();
        if (t < CBN) tmp[t] += v;
        __syncthreads();
    }
    if (t < CBN) { base_f[t] = (t ? tmp[t - 1] : 0); cur_f[t] = base_f[t]; }
    __syncthreads();
    // pass B: scatter into LDS staging. skey = (e<<12)|slot (e<32768, slot<4096)
    for (int i = t; i < ncb; i += 256) {
        int ev = ebe[gb + i];
        int f  = ev & 127;
        int pos = atomicAdd(&cur_f[f], 1);
        if (pos < CAP) {
            float2 r = ebws[gb + i];
            skey[pos] = ((ev >> 7) << 12) | pos;
            sw[pos] = r.x;
            sy[pos] = r.y;
        }
    }
    __syncthreads();
    // per-node insertion sort by edge id + deg in sorted order
    if (t < CBN) {
        int b0 = base_f[t], k = cnt_f[t];
        for (int i = 1; i < k; i++) {
            int v = skey[b0 + i];
            int j = i - 1;
            while (j >= 0) {
                int u = skey[b0 + j];
                if (u > v) { skey[b0 + j + 1] = u; j--; } else break;
            }
            skey[b0 + j + 1] = v;
        }
        float s = 0.0f;
        for (int i = 0; i < k; i++) s += sw[skey[b0 + i] & 4095];
        float deg = s + 1.0f;                 // matches ref: segment_sum(...) + 1.0
        int node = g * NPG + cb * CBN + t;
        is_arr[node] = 1.0f / sqrtf(deg);
        ptr[node] = (int)gb + b0;
        cnt[node] = k;
    }
    __syncthreads();
    // coalesced in-place writeback of the sorted payload
    for (int i = t; i < ncb; i += 256) {
        int idx = skey[i] & 4095;
        float2 r;
        r.x = sw[idx];
        r.y = sy[idx];
        ebws[gb + i] = r;
    }
}

// ---------------- K4: score — fully streaming edge payload, LDS h/is --------
__global__ __launch_bounds__(256) void k_score(const int* __restrict__ ptr,
                                               const int* __restrict__ cnt,
                                               const float2* __restrict__ pwsrc,
                                               const float* __restrict__ h,
                                               const float* __restrict__ is_arr,
                                               float* __restrict__ score) {
    __shared__ float sh_h[NPG];    // 8 KB
    __shared__ float sh_is[NPG];   // 8 KB
    int b = blockIdx.x >> 3;       // 8 blocks per graph (2048/256)
    for (int i = threadIdx.x; i < NPG; i += 256) {
        sh_h[i]  = h[(size_t)b * NPG + i];
        sh_is[i] = is_arr[(size_t)b * NPG + i];
    }
    __syncthreads();
    int n = blockIdx.x * 256 + threadIdx.x;
    int nl = n & (NPG - 1);
    int beg = ptr[n], k = cnt[n];
    float isd = sh_is[nl];
    float s = 0.0f;
    for (int i = 0; i < k; i++) {
        float2 r = pwsrc[beg + i];
        int sl = __float_as_int(r.y);
        float v = ((r.x * sh_is[sl]) * isd) * sh_h[sl];  // ref rounding order
        s += v;
    }
    s = s + sh_h[nl] * (isd * isd);       // self-loop term, ref rounding order
    score[n] = s;
}

// ------- K5: per-graph bitonic top-k (desc score, asc index ties) -----------
__global__ __launch_bounds__(1024) void k_topk(const float* __restrict__ score,
                                               int* __restrict__ topk,
                                               int* __restrict__ new_id,
                                               float* __restrict__ pngi) {
    int b = blockIdx.x, t = threadIdx.x;
    __shared__ unsigned long long key[NPG];
    for (int i = t; i < NPG; i += 1024) {
        float s = score[b * NPG + i];
        unsigned int u = __float_as_uint(s);
        u = (u & 0x80000000u) ? ~u : (u | 0x80000000u);  // ascending-order map
        unsigned int ks = ~u;                            // descending primary
        key[i] = ((unsigned long long)ks << 32) | (unsigned int)i;
    }
    __syncthreads();
    for (int k = 2; k <= NPG; k <<= 1) {
        for (int j = k >> 1; j > 0; j >>= 1) {
            int i = ((t & ~(j - 1)) << 1) | (t & (j - 1));
            int p = i | j;
            bool up = ((i & k) == 0);
            unsigned long long a = key[i], c = key[p];
            if ((a > c) == up) { key[i] = c; key[p] = a; }
            __syncthreads();
        }
    }
    int local = (int)(key[t] & 0xFFFFFFFFu);
    int node = b * NPG + local;
    int j = b * KK + t;
    topk[j] = node;
    new_id[node] = j;
    pngi[j] = (float)b;
}

// ---------------- K6: pooled_x = x[node] * tanh(score[node]) ----------------
__global__ __launch_bounds__(256) void k_gather(const float* __restrict__ x,
                                                const float* __restrict__ score,
                                                const int* __restrict__ topk,
                                                float* __restrict__ out) {
    int q = blockIdx.x * 256 + threadIdx.x;   // float4 index
    int row = q >> 5, c = q & 31;
    int node = topk[row];
    float g = tanhf(score[node]);
    const float4* x4 = (const float4*)x;
    float4 v = x4[(size_t)node * 32 + c];
    float4 o;
    o.x = v.x * g; o.y = v.y * g; o.z = v.z * g; o.w = v.w * g;
    ((float4*)out)[q] = o;
}

// ---------------- K7: edge remap + weight mask ----------------
__global__ __launch_bounds__(256) void k_edges(const int* __restrict__ src,
                                               const int* __restrict__ dst,
                                               const float* __restrict__ w,
                                               const int* __restrict__ new_id,
                                               float* __restrict__ pei0,
                                               float* __restrict__ pei1,
                                               float* __restrict__ pew) {
    int e = blockIdx.x * 256 + threadIdx.x;
    int s = src[e], d = dst[e];
    int ns = new_id[s], nd = new_id[d];
    bool m = (ns >= 0) && (nd >= 0);
    pei0[e] = m ? (float)ns : -1.0f;
    pei1[e] = m ? (float)nd : -1.0f;
    pew[e]  = m ? w[e] : 0.0f;
}

extern "C" void kernel_launch(void* const* d_in, const int* in_sizes, int n_in,
                              void* d_out, int out_size, void* d_ws, size_t ws_size,
                              hipStream_t stream) {
    const float* x   = (const float*)d_in[0];
    const int*   ei  = (const int*)d_in[1];
    const float* w   = (const float*)d_in[2];
    // d_in[3] = node_graph_index (unused: graphs are uniform)
    const float* W   = (const float*)d_in[4];
    const int* src = ei;
    const int* dst = ei + ETOT;

    // workspace layout (same footprint as before: ~114 MB)
    char* ws = (char*)d_ws;
    float*  h      = (float*)(ws);                 // N floats
    float*  is_arr = h + NTOT;                     // N floats
    float*  score  = is_arr + NTOT;                // N floats
    int*    cnt    = (int*)(score + NTOT);         // N ints
    int*    ptr    = cnt + NTOT;                   // N ints
    int*    new_id = ptr + NTOT;                   // N ints
    int*    topk   = new_id + NTOT;                // B*K ints
    int*    ebe    = topk + (size_t)NB * KK;       // E ints (coarse records: keys)
    float2* ebws   = (float2*)(ebe + (size_t)ETOT);// E float2 (coarse records; becomes pwsrc)
    // coarse bucket tables alias topk (dead until k_topk, consumed by k_fine)
    int* cptr_g = topk;                            // NB*16 ints
    int* ccnt_g = topk + NB * NCB;                 // NB*16 ints

    // output layout (all float32)
    float* out_px   = (float*)d_out;                       // [B*K, D]
    float* out_pei0 = out_px + (size_t)NB * KK * DD;       // [E]
    float* out_pei1 = out_pei0 + ETOT;                     // [E]
    float* out_pew  = out_pei1 + ETOT;                     // [E]
    float* out_pngi = out_pew + ETOT;                      // [B*K]

    hipMemsetAsync(new_id, 0xFF, (size_t)NTOT * 4, stream);  // -1

    k_h<<<NTOT / 8, 256, 0, stream>>>(x, W, h);
    k_part<<<NB, 1024, 0, stream>>>(src, dst, w, cptr_g, ccnt_g, ebws, ebe);
    k_fine<<<NB * NCB, 256, 0, stream>>>(cptr_g, ccnt_g, ebws, ebe, ptr, cnt, is_arr);
    k_score<<<NTOT / 256, 256, 0, stream>>>(ptr, cnt, ebws, h, is_arr, score);
    k_topk<<<NB, 1024, 0, stream>>>(score, topk, new_id, out_pngi);
    k_gather<<<(NB * KK * DD / 4) / 256, 256, 0, stream>>>(x, score, topk, out_px);
    k_edges<<<ETOT / 256, 256, 0, stream>>>(src, dst, w, new_id, out_pei0, out_pei1, out_pew);
}

// Round 5
// 778.256 us; speedup vs baseline: 1.5376x; 1.0195x over previous
//
#include <hip/hip_runtime.h>
#include <math.h>

#define NB   256
#define NPG  2048
#define DD   128
#define DEGC 16
#define NTOT (NB * NPG)      // 524288 nodes
#define ETOT (NTOT * DEGC)   // 8388608 edges
#define KK   (NPG / 2)       // 1024 kept per graph
#define EPG  (NPG * DEGC)    // 32768 edges per graph
#define NCB  16              // coarse buckets per graph (128 nodes each)
#define CBN  128             // nodes per coarse bucket
#define CAP  2560            // chunk capacity: mean 2048, sd 44 -> mean+11.6sd

// ---------------- K1: h = x @ W  (half-wave per node, float4) ----------------
__global__ __launch_bounds__(256) void k_h(const float* __restrict__ x,
                                           const float* __restrict__ W,
                                           float* __restrict__ h) {
    int lane = threadIdx.x & 63;
    int wv   = threadIdx.x >> 6;
    int half = lane >> 5;
    int sub  = lane & 31;
    int node = blockIdx.x * 8 + wv * 2 + half;
    const float4* x4 = (const float4*)x;
    const float4* W4 = (const float4*)W;
    float4 xv = x4[(size_t)node * 32 + sub];
    float4 wv4 = W4[sub];
    float p = xv.x * wv4.x + xv.y * wv4.y + xv.z * wv4.z + xv.w * wv4.w;
    #pragma unroll
    for (int off = 16; off >= 1; off >>= 1) p += __shfl_xor(p, off, 64);
    if (sub == 0) h[node] = p;
}

// ---- K2a: coarse partition, one block per graph. Edges scattered to 16
//      append-frontiers (dense lines -> no write amplification). Record:
//      ebws = {w, src_local as float bits}, ebe = (e_local<<7)|dst_low7. ----
__global__ __launch_bounds__(1024) void k_part(const int* __restrict__ src,
                                               const int* __restrict__ dst,
                                               const float* __restrict__ w,
                                               int* __restrict__ cptr_g,
                                               int* __restrict__ ccnt_g,
                                               float2* __restrict__ ebws,
                                               int* __restrict__ ebe) {
    int g = blockIdx.x, t = threadIdx.x;
    __shared__ int ccnt[NCB];
    __shared__ int ccur[NCB];
    const int*   dslab = dst + (size_t)g * EPG;
    const int*   sslab = src + (size_t)g * EPG;
    const float* wslab = w   + (size_t)g * EPG;
    if (t < NCB) ccnt[t] = 0;
    __syncthreads();
    // phase 1: count coarse buckets; keep local dst in registers (full unroll)
    int dloc[EPG / 1024];
    #pragma unroll
    for (int i = 0; i < EPG / 1024; i++) {
        dloc[i] = dslab[i * 1024 + t] - g * NPG;
        atomicAdd(&ccnt[dloc[i] >> 7], 1);
    }
    __syncthreads();
    // phase 2: tiny serial scan of 16
    if (t == 0) {
        int acc = 0;
        for (int b = 0; b < NCB; b++) {
            int c = ccnt[b];
            cptr_g[g * NCB + b] = acc;
            ccnt_g[g * NCB + b] = c;
            ccur[b] = acc;
            acc += c;
        }
    }
    __syncthreads();
    // phase 3: scatter to coarse frontiers
    size_t gb = (size_t)g * EPG;
    #pragma unroll
    for (int i = 0; i < EPG / 1024; i++) {
        int e = i * 1024 + t;
        int d = dloc[i];
        int pos = atomicAdd(&ccur[d >> 7], 1);
        ebe[gb + pos] = (e << 7) | (d & 127);
        float2 r;
        r.x = wslab[e];
        r.y = __int_as_float(sslab[e] - g * NPG);
        ebws[gb + pos] = r;
    }
}

// ---- K2b: fine scatter + per-node sort + deg, one block per (graph, coarse
//      bucket). Stages the ~16 KB chunk in LDS, sorts each node's edges asc by
//      edge id (np.add.at order), computes deg in sorted order, writes the
//      sorted payload back IN PLACE (coalesced) -> ebws becomes pwsrc. ----
__global__ __launch_bounds__(256) void k_fine(const int* __restrict__ cptr_g,
                                              const int* __restrict__ ccnt_g,
                                              float2* ebws,            // read+write (in place)
                                              const int* __restrict__ ebe,
                                              int* __restrict__ ptr,
                                              int* __restrict__ cnt,
                                              float* __restrict__ is_arr) {
    __shared__ int   skey[CAP];
    __shared__ float sw[CAP];
    __shared__ float sy[CAP];
    __shared__ int cnt_f[CBN];
    __shared__ int cur_f[CBN];
    __shared__ int base_f[CBN];
    __shared__ int tmp[CBN];
    int g = blockIdx.x >> 4, cb = blockIdx.x & 15, t = threadIdx.x;
    int cb_base = cptr_g[g * NCB + cb];
    int ncb     = ccnt_g[g * NCB + cb];
    size_t gb = (size_t)g * EPG + cb_base;
    if (t < CBN) cnt_f[t] = 0;
    __syncthreads();
    // pass A: fine counts
    for (int i = t; i < ncb; i += 256) atomicAdd(&cnt_f[ebe[gb + i] & 127], 1);
    __syncthreads();
    // scan 128 (Hillis-Steele)
    if (t < CBN) tmp[t] = cnt_f[t];
    __syncthreads();
    for (int off = 1; off < CBN; off <<= 1) {
        int v = 0;
        if (t < CBN && t >= off) v = tmp[t - off];
        __syncthreads();
        if (t < CBN) tmp[t] += v;
        __syncthreads();
    }
    if (t < CBN) { base_f[t] = (t ? tmp[t - 1] : 0); cur_f[t] = base_f[t]; }
    __syncthreads();
    // pass B: scatter into LDS staging. skey = (e<<12)|slot (e<32768, slot<4096)
    for (int i = t; i < ncb; i += 256) {
        int ev = ebe[gb + i];
        int f  = ev & 127;
        int pos = atomicAdd(&cur_f[f], 1);
        if (pos < CAP) {
            float2 r = ebws[gb + i];
            skey[pos] = ((ev >> 7) << 12) | pos;
            sw[pos] = r.x;
            sy[pos] = r.y;
        }
    }
    __syncthreads();
    // per-node insertion sort by edge id + deg in sorted order
    if (t < CBN) {
        int b0 = base_f[t], k = cnt_f[t];
        for (int i = 1; i < k; i++) {
            int v = skey[b0 + i];
            int j = i - 1;
            while (j >= 0) {
                int u = skey[b0 + j];
                if (u > v) { skey[b0 + j + 1] = u; j--; } else break;
            }
            skey[b0 + j + 1] = v;
        }
        float s = 0.0f;
        for (int i = 0; i < k; i++) s += sw[skey[b0 + i] & 4095];
        float deg = s + 1.0f;                 // matches ref: segment_sum(...) + 1.0
        int node = g * NPG + cb * CBN + t;
        is_arr[node] = 1.0f / sqrtf(deg);
        ptr[node] = (int)gb + b0;
        cnt[node] = k;
    }
    __syncthreads();
    // coalesced in-place writeback of the sorted payload
    for (int i = t; i < ncb; i += 256) {
        int idx = skey[i] & 4095;
        float2 r;
        r.x = sw[idx];
        r.y = sy[idx];
        ebws[gb + i] = r;
    }
}

// ---- K3: fused tail — score + bitonic top-k + gather + edge remap, one
//      1024-thread block per graph. score/new_id/topk never touch global:
//      scores live in the (invertible) sort keys, new_id in LDS. ----
__global__ __launch_bounds__(1024) void k_final(const int* __restrict__ ptr,
                                                const int* __restrict__ cnt,
                                                const float2* __restrict__ pwsrc,
                                                const float* __restrict__ h,
                                                const float* __restrict__ is_arr,
                                                const float* __restrict__ x,
                                                const int* __restrict__ src,
                                                const int* __restrict__ dst,
                                                const float* __restrict__ w,
                                                float* __restrict__ out_px,
                                                float* __restrict__ out_pei0,
                                                float* __restrict__ out_pei1,
                                                float* __restrict__ out_pew,
                                                float* __restrict__ out_pngi) {
    __shared__ float sh_h[NPG];                 // 8 KB
    __shared__ float sh_is[NPG];                // 8 KB
    __shared__ unsigned long long key[NPG];     // 16 KB
    __shared__ int new_local[NPG];              // 8 KB
    int g = blockIdx.x, t = threadIdx.x;
    // phase 1: stage h / is for the whole graph
    for (int i = t; i < NPG; i += 1024) {
        sh_h[i]  = h[(size_t)g * NPG + i];
        sh_is[i] = is_arr[(size_t)g * NPG + i];
    }
    __syncthreads();
    // phase 2: score, 2 nodes per thread (identical expression/order as before)
    float sc[2];
    #pragma unroll
    for (int r = 0; r < 2; r++) {
        int nl = t + r * 1024;
        int n = g * NPG + nl;
        int beg = ptr[n], k = cnt[n];
        float isd = sh_is[nl];
        float s = 0.0f;
        for (int i = 0; i < k; i++) {
            float2 rr = pwsrc[beg + i];
            int sl = __float_as_int(rr.y);
            float v = ((rr.x * sh_is[sl]) * isd) * sh_h[sl];  // ref rounding order
            s += v;
        }
        sc[r] = s + sh_h[nl] * (isd * isd);   // self-loop term, ref rounding order
    }
    __syncthreads();
    // phase 3: build sort keys (invertible score map) + init new_local
    #pragma unroll
    for (int r = 0; r < 2; r++) {
        int nl = t + r * 1024;
        unsigned int u = __float_as_uint(sc[r]);
        u = (u & 0x80000000u) ? ~u : (u | 0x80000000u);  // ascending-order map
        unsigned int ks = ~u;                            // descending primary
        key[nl] = ((unsigned long long)ks << 32) | (unsigned int)nl;
        new_local[nl] = -1;
    }
    __syncthreads();
    // phase 4: bitonic sort 2048 (desc score, asc index ties)
    for (int k = 2; k <= NPG; k <<= 1) {
        for (int j = k >> 1; j > 0; j >>= 1) {
            int i = ((t & ~(j - 1)) << 1) | (t & (j - 1));
            int p = i | j;
            bool up = ((i & k) == 0);
            unsigned long long a = key[i], c = key[p];
            if ((a > c) == up) { key[i] = c; key[p] = a; }
            __syncthreads();
        }
    }
    // phase 5: top-KK -> new_local, pngi
    {
        int local = (int)(key[t] & 0xFFFFFFFFu);
        new_local[local] = t;
        out_pngi[g * KK + t] = (float)g;
    }
    __syncthreads();
    // phase 6: pooled_x = x[node] * tanh(score) (score recovered from key bits)
    const float4* x4 = (const float4*)x;
    float4* o4 = (float4*)out_px;
    for (int q = t; q < KK * (DD / 4); q += 1024) {
        int row = q >> 5, c = q & 31;
        unsigned long long kk = key[row];
        int local = (int)(kk & 0xFFFFFFFFu);
        unsigned int u = ~(unsigned int)(kk >> 32);
        unsigned int orig = (u & 0x80000000u) ? (u ^ 0x80000000u) : ~u;
        float gm = tanhf(__uint_as_float(orig));
        float4 xv = x4[((size_t)g * NPG + local) * 32 + c];
        float4 o;
        o.x = xv.x * gm; o.y = xv.y * gm; o.z = xv.z * gm; o.w = xv.w * gm;
        o4[((size_t)g * KK + row) * 32 + c] = o;
    }
    // phase 7: edge remap + weight mask (new_id lookups in LDS)
    size_t eb = (size_t)g * EPG;
    for (int e = t; e < EPG; e += 1024) {
        int sl = src[eb + e] - g * NPG;
        int dl = dst[eb + e] - g * NPG;
        int ns = new_local[sl], nd = new_local[dl];
        bool m = (ns >= 0) && (nd >= 0);
        out_pei0[eb + e] = m ? (float)(g * KK + ns) : -1.0f;
        out_pei1[eb + e] = m ? (float)(g * KK + nd) : -1.0f;
        out_pew[eb + e]  = m ? w[eb + e] : 0.0f;
    }
}

extern "C" void kernel_launch(void* const* d_in, const int* in_sizes, int n_in,
                              void* d_out, int out_size, void* d_ws, size_t ws_size,
                              hipStream_t stream) {
    const float* x   = (const float*)d_in[0];
    const int*   ei  = (const int*)d_in[1];
    const float* w   = (const float*)d_in[2];
    // d_in[3] = node_graph_index (unused: graphs are uniform)
    const float* W   = (const float*)d_in[4];
    const int* src = ei;
    const int* dst = ei + ETOT;

    // workspace layout (offsets identical to the passing round-4 layout;
    // score/new_id slots now dead but kept to preserve footprint)
    char* ws = (char*)d_ws;
    float*  h      = (float*)(ws);                 // N floats
    float*  is_arr = h + NTOT;                     // N floats
    float*  score_dead = is_arr + NTOT;            // N floats (unused)
    int*    cnt    = (int*)(score_dead + NTOT);    // N ints
    int*    ptr    = cnt + NTOT;                   // N ints
    int*    new_id_dead = ptr + NTOT;              // N ints (unused)
    int*    tkreg  = new_id_dead + NTOT;           // B*K ints (coarse tables alias)
    int*    ebe    = tkreg + (size_t)NB * KK;      // E ints (coarse records: keys)
    float2* ebws   = (float2*)(ebe + (size_t)ETOT);// E float2 (coarse records; becomes pwsrc)
    int* cptr_g = tkreg;                           // NB*16 ints
    int* ccnt_g = tkreg + NB * NCB;                // NB*16 ints

    // output layout (all float32)
    float* out_px   = (float*)d_out;                       // [B*K, D]
    float* out_pei0 = out_px + (size_t)NB * KK * DD;       // [E]
    float* out_pei1 = out_pei0 + ETOT;                     // [E]
    float* out_pew  = out_pei1 + ETOT;                     // [E]
    float* out_pngi = out_pew + ETOT;                      // [B*K]

    k_h<<<NTOT / 8, 256, 0, stream>>>(x, W, h);
    k_part<<<NB, 1024, 0, stream>>>(src, dst, w, cptr_g, ccnt_g, ebws, ebe);
    k_fine<<<NB * NCB, 256, 0, stream>>>(cptr_g, ccnt_g, ebws, ebe, ptr, cnt, is_arr);
    k_final<<<NB, 1024, 0, stream>>>(ptr, cnt, ebws, h, is_arr, x, src, dst, w,
                                     out_px, out_pei0, out_pei1, out_pew, out_pngi);
}